// Round 6
// baseline (3507.931 us; speedup 1.0000x reference)
//
#include <hip/hip_runtime.h>
#include <hip/hip_bf16.h>

typedef unsigned short u16;
typedef __bf16 bf16x8 __attribute__((ext_vector_type(8)));
typedef float floatx4 __attribute__((ext_vector_type(4)));
typedef __hip_bfloat16 bf;

constexpr int LDP  = 40;          // padded LDS row stride (elems); 80 B -> bank
                                  // starts {0,20,8,28,16,4,24,12}*4B over 8 rows
                                  // => only 2-way aliasing (free per m136)
constexpr int TSZ  = 128 * LDP;   // one LDS tile buffer, elems

__device__ __forceinline__ __bf16 f2b(float f) {
    __hip_bfloat16 h = __float2bfloat16(f);
    return *reinterpret_cast<__bf16*>(&h);
}
__device__ __forceinline__ bf16x8 ld8(const bf* p) {
    return *(const bf16x8*)(const void*)p;
}
__device__ __forceinline__ bf16x8 ld8(const float* p) {
    float4 a = ((const float4*)p)[0];
    float4 b = ((const float4*)p)[1];
    bf16x8 r;
    r[0] = f2b(a.x); r[1] = f2b(a.y); r[2] = f2b(a.z); r[3] = f2b(a.w);
    r[4] = f2b(b.x); r[5] = f2b(b.y); r[6] = f2b(b.z); r[7] = f2b(b.w);
    return r;
}

__device__ __forceinline__ void storev(float* p, float v) { *p = v; }
__device__ __forceinline__ void storev(bf* p, float v)    { *p = __float2bfloat16(v); }

// ============================================================================
// NT GEMM core: C[m,n] = scale * sum_k A[m,k]*B[n,k].  128x128 tile, BK=32,
// 256 thr = 4 waves, 4x4 mfma_f32_16x16x32_bf16 per wave.  Double-buffered
// LDS (padded stride 40), ONE barrier per K-iter, depth-2 register pipeline:
// tile i+2's global loads issue at iter i, are stored to LDS at iter i+1,
// computed at iter i+2 -> ~2 compute phases of load-latency hiding.
// ============================================================================
template <typename TA, typename TB, typename OutT>
__device__ __forceinline__ void gemm_core(
    const TA* __restrict__ A, const TB* __restrict__ B, OutT* __restrict__ C,
    int K, int N, int m_blk, int n_blk, float scale, u16* As, u16* Bs)
{
    const int tid  = threadIdx.x;
    const int wave = tid >> 6;
    const int lane = tid & 63;

    // staging: thread covers tile rows r0 and r0+64, 8 elems at col (tid&3)*8
    const int r0  = tid >> 2;
    const int cc  = (tid & 3) * 8;
    const TA* Ag0 = A + (long)(m_blk + r0) * K + cc;
    const TA* Ag1 = Ag0 + (long)64 * K;
    const TB* Bg0 = B + (long)(n_blk + r0) * K + cc;
    const TB* Bg1 = Bg0 + (long)64 * K;
    const int wr0 = r0 * LDP + cc;          // LDS elem offset, row r0
    const int wr1 = wr0 + 64 * LDP;

    floatx4 acc[4][4];
#pragma unroll
    for (int i = 0; i < 4; i++)
#pragma unroll
        for (int j = 0; j < 4; j++) acc[i][j] = (floatx4){0.f, 0.f, 0.f, 0.f};

    const int wm = (wave >> 1) * 64;
    const int wn = (wave & 1) * 64;
    const int fr = lane & 15;
    const int fk = (lane >> 4) * 8;

    const int T = K >> 5;                   // K-iterations
    bf16x8 ra[2][2], rb[2][2];              // reg sets: tile t lives in set t&1

    // prologue: tile0 -> regs -> LDS buf0; issue tile1 -> regs set1
    ra[0][0] = ld8(Ag0); ra[0][1] = ld8(Ag1);
    rb[0][0] = ld8(Bg0); rb[0][1] = ld8(Bg1);
    *(bf16x8*)&As[wr0] = ra[0][0]; *(bf16x8*)&As[wr1] = ra[0][1];
    *(bf16x8*)&Bs[wr0] = rb[0][0]; *(bf16x8*)&Bs[wr1] = rb[0][1];
    if (T > 1) {
        ra[1][0] = ld8(Ag0 + 32); ra[1][1] = ld8(Ag1 + 32);
        rb[1][0] = ld8(Bg0 + 32); rb[1][1] = ld8(Bg1 + 32);
    }
    __syncthreads();

    for (int i = 0; i < T; i++) {
        const int cur = i & 1;
        // store tile i+1 (set (i+1)&1) into the buffer NOT being computed.
        // Safe: its old contents (tile i-1) were fully read before the
        // barrier that ended iter i-1.
        if (i + 1 < T) {
            const int nb = 1 - cur;
            u16* An = As + nb * TSZ; u16* Bn = Bs + nb * TSZ;
            *(bf16x8*)&An[wr0] = ra[nb][0]; *(bf16x8*)&An[wr1] = ra[nb][1];
            *(bf16x8*)&Bn[wr0] = rb[nb][0]; *(bf16x8*)&Bn[wr1] = rb[nb][1];
        }
        // issue tile i+2 into set cur (its old tile i is already in LDS)
        if (i + 2 < T) {
            const long ko = (long)(i + 2) * 32;
            ra[cur][0] = ld8(Ag0 + ko); ra[cur][1] = ld8(Ag1 + ko);
            rb[cur][0] = ld8(Bg0 + ko); rb[cur][1] = ld8(Bg1 + ko);
        }
        // compute tile i from buf cur
        const u16* Ac = As + cur * TSZ;
        const u16* Bc = Bs + cur * TSZ;
        bf16x8 af[4], bv[4];
#pragma unroll
        for (int q = 0; q < 4; q++)
            af[q] = *(const bf16x8*)&Ac[(wm + q * 16 + fr) * LDP + fk];
#pragma unroll
        for (int j = 0; j < 4; j++)
            bv[j] = *(const bf16x8*)&Bc[(wn + j * 16 + fr) * LDP + fk];
#pragma unroll
        for (int q = 0; q < 4; q++)
#pragma unroll
            for (int j = 0; j < 4; j++)
                acc[q][j] = __builtin_amdgcn_mfma_f32_16x16x32_bf16(
                    af[q], bv[j], acc[q][j], 0, 0, 0);
        __syncthreads();   // single barrier: publishes tile i+1, retires buf cur
    }

    // epilogue: C/D layout col=lane&15, row=(lane>>4)*4+reg  [m89/m91]
    const int c_col0 = n_blk + wn + fr;
    const int c_row0 = m_blk + wm + (lane >> 4) * 4;
#pragma unroll
    for (int q = 0; q < 4; q++)
#pragma unroll
        for (int r = 0; r < 4; r++) {
            const long row = c_row0 + q * 16 + r;
#pragma unroll
            for (int j = 0; j < 4; j++)
                storev(&C[row * N + c_col0 + j * 16], acc[q][j][r] * scale);
        }
}

// generic z-batched wrapper
template <typename TA, typename TB, typename OutT>
__global__ __launch_bounds__(256)
void gemm_z(const TA* __restrict__ A, const TB* __restrict__ B,
            OutT* __restrict__ C, int K, int N,
            long sA, long sB, long sC, float scale)
{
    __shared__ __align__(16) u16 As[2 * TSZ];
    __shared__ __align__(16) u16 Bs[2 * TSZ];
    gemm_core(A + blockIdx.z * sA, B + blockIdx.z * sB, C + blockIdx.z * sC,
              K, N, blockIdx.y * 128, blockIdx.x * 128, scale, As, Bs);
}

// Q and K projections fused into one launch (z selects), doubling occupancy
__global__ __launch_bounds__(256)
void gemm_qk(const float* __restrict__ x, const float* __restrict__ mem,
             const float* __restrict__ Wq, const float* __restrict__ Wk,
             bf* __restrict__ Q, bf* __restrict__ Kp, float qscale)
{
    __shared__ __align__(16) u16 As[2 * TSZ];
    __shared__ __align__(16) u16 Bs[2 * TSZ];
    const int z = blockIdx.z;
    gemm_core(z ? mem : x, z ? Wk : Wq, z ? Kp : Q,
              1024, 1024, blockIdx.y * 128, blockIdx.x * 128,
              z ? 1.f : qscale, As, Bs);
}

// ============================================================================
// In-place bf16 row softmax over 2048 logits; one block per row; each thread
// rewrites exactly the elements it read -> race-free.
// ============================================================================
__global__ __launch_bounds__(256)
void softmax_rows_2048(bf* __restrict__ X)
{
    const long row = blockIdx.x;
    const int t = threadIdx.x;
    const int wave = t >> 6, lane = t & 63;
    __shared__ float red[8];

    float v[8];
    float m = -1e30f;
#pragma unroll
    for (int i = 0; i < 8; i++) {
        v[i] = __bfloat162float(X[row * 2048 + t + i * 256]);
        m = fmaxf(m, v[i]);
    }
#pragma unroll
    for (int o = 32; o > 0; o >>= 1) m = fmaxf(m, __shfl_xor(m, o, 64));
    if (lane == 0) red[wave] = m;
    __syncthreads();
    m = fmaxf(fmaxf(red[0], red[1]), fmaxf(red[2], red[3]));

    float s = 0.f;
#pragma unroll
    for (int i = 0; i < 8; i++) { v[i] = __expf(v[i] - m); s += v[i]; }
#pragma unroll
    for (int o = 32; o > 0; o >>= 1) s += __shfl_xor(s, o, 64);
    if (lane == 0) red[4 + wave] = s;
    __syncthreads();
    s = red[4] + red[5] + red[6] + red[7];

    const float inv = 1.f / s;
#pragma unroll
    for (int i = 0; i < 8; i++)
        X[row * 2048 + t + i * 256] = __float2bfloat16(v[i] * inv);
}

// ============================================================================
// Pipeline (9 dispatches):
//   1. QK fused proj (z=2, 1024 blk)      x,mem fp32 -> Q,Kp bf16
//   2. Vt proj       (z=4,  512 blk)      Vt[b][e,m] = Wv[e,:].mem[b][m,:]
//   3. per batch-PAIR g in {0,1}:
//        logits z=2 (512 blk) -> Lg bf16 [2][2048][2048]
//        softmax 4096 blk in-place
//        AO z=2     (256 blk) -> AO bf16 (aliases Q: Q[pair g] dead)
//   4. final proj    (512 blk)            out fp32
// Workspace: Q/AO 16 + Kp 16 + Vt 16 + Lg 16 = 64 MiB (same as passing R5).
// ============================================================================
extern "C" void kernel_launch(void* const* d_in, const int* in_sizes, int n_in,
                              void* d_out, int out_size, void* d_ws, size_t ws_size,
                              hipStream_t stream)
{
    const float* x   = (const float*)d_in[0];  // [4,2048,1024] fp32
    const float* mem = (const float*)d_in[1];
    const float* Wq  = (const float*)d_in[2];  // [1024,1024] fp32 [out,in]
    const float* Wk  = (const float*)d_in[3];
    const float* Wv  = (const float*)d_in[4];
    const float* Wo  = (const float*)d_in[5];
    float* out = (float*)d_out;                // fp32 reference output

    constexpr int  B = 4, L = 2048, D = 1024;
    constexpr long LD = (long)L * D;           // 2M elems
    constexpr long LL = (long)L * L;           // 4M elems
    constexpr size_t CH = 1u << 24;

    char* ws = (char*)d_ws;
    bf* Q  = (bf*)(ws + 0 * CH);   // [4][2048][1024]; AO aliases
    bf* Kp = (bf*)(ws + 1 * CH);   // [4][2048][1024]
    bf* Vt = (bf*)(ws + 2 * CH);   // [4][1024][2048]
    bf* Lg = (bf*)(ws + 3 * CH);   // [2][2048][2048] logits->P in place
    bf* AO = Q;

    dim3 blk(256);
    const float qscale = 0.03125f;  // 1024^-0.5

    // 1. Q = x@Wq^T*s, K = mem@Wk^T  (fused, z picks operands)
    gemm_qk<<<dim3(D / 128, B * L / 128, 2), blk, 0, stream>>>(
        x, mem, Wq, Wk, Q, Kp, qscale);

    // 2. Vt[b] = Wv (.) mem[b]^T : M=D, N=L, K=D
    gemm_z<float, float, bf><<<dim3(L / 128, D / 128, B), blk, 0, stream>>>(
        Wv, mem, Vt, D, L, 0, LD, (long)D * L, 1.f);

    for (int g = 0; g < 2; g++) {
        bf* Qg  = Q  + (long)g * 2 * LD;
        bf* Kg  = Kp + (long)g * 2 * LD;
        bf* Vg  = Vt + (long)g * 2 * (long)D * L;
        bf* AOg = AO + (long)g * 2 * LD;
        // logits[z][q,m] = Qg[z][q,:].Kg[z][m,:] : M=N=L, K=D
        gemm_z<bf, bf, bf><<<dim3(L / 128, L / 128, 2), blk, 0, stream>>>(
            Qg, Kg, Lg, D, L, LD, LD, LL, 1.f);
        softmax_rows_2048<<<dim3(2 * L), blk, 0, stream>>>(Lg);
        // AO[z][q,e] = P[z][q,:].Vg[z][e,:] : M=L, N=D, K=L
        gemm_z<bf, bf, bf><<<dim3(D / 128, L / 128, 2), blk, 0, stream>>>(
            Lg, Vg, AOg, L, D, LL, (long)D * L, LD, 1.f);
    }

    // 4. out = AO @ Wo^T : M=B*L, N=D, K=D
    gemm_z<bf, float, float><<<dim3(D / 128, B * L / 128, 1), blk, 0, stream>>>(
        AO, Wo, out, D, D, 0, 0, 0, 1.f);
}

// Round 7
// 402.966 us; speedup vs baseline: 8.7053x; 8.7053x over previous
//
#include <hip/hip_runtime.h>
#include <hip/hip_bf16.h>

typedef unsigned short u16;
typedef __bf16 bf16x8 __attribute__((ext_vector_type(8)));
typedef float floatx4 __attribute__((ext_vector_type(4)));
typedef __hip_bfloat16 bf;

constexpr int LDP = 40;          // padded LDS row stride (elems); 80 B rows ->
                                 // read start-banks {0,20,8,28,16,4,24,12}:
                                 // full coverage, 2-way aliasing (free, m136)
constexpr int TSZ = 128 * LDP;   // one LDS tile buffer, elems

__device__ __forceinline__ __bf16 f2b(float f) {
    __hip_bfloat16 h = __float2bfloat16(f);
    return *reinterpret_cast<__bf16*>(&h);
}
__device__ __forceinline__ bf16x8 ld8(const bf* p) {
    return *(const bf16x8*)(const void*)p;
}
__device__ __forceinline__ bf16x8 ld8(const float* p) {
    float4 a = ((const float4*)p)[0];
    float4 b = ((const float4*)p)[1];
    bf16x8 r;
    r[0] = f2b(a.x); r[1] = f2b(a.y); r[2] = f2b(a.z); r[3] = f2b(a.w);
    r[4] = f2b(b.x); r[5] = f2b(b.y); r[6] = f2b(b.z); r[7] = f2b(b.w);
    return r;
}

__device__ __forceinline__ void storev(float* p, float v) { *p = v; }
__device__ __forceinline__ void storev(bf* p, float v)    { *p = __float2bfloat16(v); }

// one 128x128x32 tile's MFMA work; ALL indices compile-time static shapes
__device__ __forceinline__ void mfma_tile(const u16* Ac, const u16* Bc,
                                          floatx4 (&acc)[4][4],
                                          int wm, int wn, int fr, int fk)
{
    bf16x8 af[4], bv[4];
#pragma unroll
    for (int q = 0; q < 4; q++)
        af[q] = *(const bf16x8*)&Ac[(wm + q * 16 + fr) * LDP + fk];
#pragma unroll
    for (int j = 0; j < 4; j++)
        bv[j] = *(const bf16x8*)&Bc[(wn + j * 16 + fr) * LDP + fk];
#pragma unroll
    for (int q = 0; q < 4; q++)
#pragma unroll
        for (int j = 0; j < 4; j++)
            acc[q][j] = __builtin_amdgcn_mfma_f32_16x16x32_bf16(
                af[q], bv[j], acc[q][j], 0, 0, 0);
}

// ============================================================================
// NT GEMM core: C[m,n] = scale * sum_k A[m,k]*B[n,k].  128x128 tile, BK=32,
// 256 thr = 4 waves, 4x4 mfma_f32_16x16x32_bf16 per wave.  Double-buffered
// LDS, one barrier per K-step, depth-2 register pipeline — K-loop MANUALLY
// UNROLLED x2 so every register set and LDS buffer offset is STATIC (R6's
// dynamic-indexed reg arrays lowered to select chains: 41% VALUBusy, 10x).
// Requires T = K/32 even (K in {1024, 2048} here).
// ============================================================================
template <typename TA, typename TB, typename OutT>
__device__ __forceinline__ void gemm_core(
    const TA* __restrict__ A, const TB* __restrict__ B, OutT* __restrict__ C,
    int K, int N, int m_blk, int n_blk, float scale, u16* As, u16* Bs)
{
    const int tid  = threadIdx.x;
    const int wave = tid >> 6;
    const int lane = tid & 63;

    // staging: thread covers tile rows r0 and r0+64, 8 elems at col (tid&3)*8
    const int r0  = tid >> 2;
    const int cc  = (tid & 3) * 8;
    const TA* Ag0 = A + (long)(m_blk + r0) * K + cc;
    const TA* Ag1 = Ag0 + (long)64 * K;
    const TB* Bg0 = B + (long)(n_blk + r0) * K + cc;
    const TB* Bg1 = Bg0 + (long)64 * K;
    const int wr0 = r0 * LDP + cc;
    const int wr1 = wr0 + 64 * LDP;

    floatx4 acc[4][4];
#pragma unroll
    for (int q = 0; q < 4; q++)
#pragma unroll
        for (int j = 0; j < 4; j++) acc[q][j] = (floatx4){0.f, 0.f, 0.f, 0.f};

    const int wm = (wave >> 1) * 64;
    const int wn = (wave & 1) * 64;
    const int fr = lane & 15;
    const int fk = (lane >> 4) * 8;

    const int T = K >> 5;  // even, >= 32

    // two register sets with STATIC names: set0 = {a0,a1,b0,b1}, set1 = {c0..d1}
    bf16x8 a0, a1, b0, b1, c0, c1, d0, d1;

    // prologue: tile0 -> set0 -> buf0 ; tile1 -> set1 (regs only)
    a0 = ld8(Ag0);      a1 = ld8(Ag1);
    b0 = ld8(Bg0);      b1 = ld8(Bg1);
    *(bf16x8*)&As[wr0] = a0;  *(bf16x8*)&As[wr1] = a1;
    *(bf16x8*)&Bs[wr0] = b0;  *(bf16x8*)&Bs[wr1] = b1;
    c0 = ld8(Ag0 + 32); c1 = ld8(Ag1 + 32);
    d0 = ld8(Bg0 + 32); d1 = ld8(Bg1 + 32);
    __syncthreads();

    int i = 0;
    for (; i + 2 < T; i += 2) {
        // phase A: publish set1 (tile i+1) -> buf1; load tile i+2 -> set0;
        //          compute tile i from buf0
        *(bf16x8*)&As[TSZ + wr0] = c0;  *(bf16x8*)&As[TSZ + wr1] = c1;
        *(bf16x8*)&Bs[TSZ + wr0] = d0;  *(bf16x8*)&Bs[TSZ + wr1] = d1;
        {
            const long ko = (long)(i + 2) * 32;
            a0 = ld8(Ag0 + ko); a1 = ld8(Ag1 + ko);
            b0 = ld8(Bg0 + ko); b1 = ld8(Bg1 + ko);
        }
        mfma_tile(As, Bs, acc, wm, wn, fr, fk);
        __syncthreads();

        // phase B: publish set0 (tile i+2) -> buf0; load tile i+3 -> set1;
        //          compute tile i+1 from buf1
        *(bf16x8*)&As[wr0] = a0;  *(bf16x8*)&As[wr1] = a1;
        *(bf16x8*)&Bs[wr0] = b0;  *(bf16x8*)&Bs[wr1] = b1;
        if (i + 3 < T) {
            const long ko = (long)(i + 3) * 32;
            c0 = ld8(Ag0 + ko); c1 = ld8(Ag1 + ko);
            d0 = ld8(Bg0 + ko); d1 = ld8(Bg1 + ko);
        }
        mfma_tile(As + TSZ, Bs + TSZ, acc, wm, wn, fr, fk);
        __syncthreads();
    }

    // epilogue: buf0 already holds tile T-2 (stored in last phase B);
    // set1 holds tile T-1 -> publish to buf1, then compute both.
    *(bf16x8*)&As[TSZ + wr0] = c0;  *(bf16x8*)&As[TSZ + wr1] = c1;
    *(bf16x8*)&Bs[TSZ + wr0] = d0;  *(bf16x8*)&Bs[TSZ + wr1] = d1;
    __syncthreads();
    mfma_tile(As, Bs, acc, wm, wn, fr, fk);
    mfma_tile(As + TSZ, Bs + TSZ, acc, wm, wn, fr, fk);

    // C-write: C/D layout col=lane&15, row=(lane>>4)*4+reg  [m89/m91]
    const int c_col0 = n_blk + wn + fr;
    const int c_row0 = m_blk + wm + (lane >> 4) * 4;
#pragma unroll
    for (int q = 0; q < 4; q++)
#pragma unroll
        for (int r = 0; r < 4; r++) {
            const long row = c_row0 + q * 16 + r;
#pragma unroll
            for (int j = 0; j < 4; j++)
                storev(&C[row * N + c_col0 + j * 16], acc[q][j][r] * scale);
        }
}

// generic z-batched wrapper
template <typename TA, typename TB, typename OutT>
__global__ __launch_bounds__(256)
void gemm_z(const TA* __restrict__ A, const TB* __restrict__ B,
            OutT* __restrict__ C, int K, int N,
            long sA, long sB, long sC, float scale)
{
    __shared__ __align__(16) u16 As[2 * TSZ];
    __shared__ __align__(16) u16 Bs[2 * TSZ];
    gemm_core(A + blockIdx.z * sA, B + blockIdx.z * sB, C + blockIdx.z * sC,
              K, N, blockIdx.y * 128, blockIdx.x * 128, scale, As, Bs);
}

// Q and K projections fused into one launch (z selects operand set)
__global__ __launch_bounds__(256)
void gemm_qk(const float* __restrict__ x, const float* __restrict__ mem,
             const float* __restrict__ Wq, const float* __restrict__ Wk,
             bf* __restrict__ Q, bf* __restrict__ Kp, float qscale)
{
    __shared__ __align__(16) u16 As[2 * TSZ];
    __shared__ __align__(16) u16 Bs[2 * TSZ];
    const int z = blockIdx.z;
    gemm_core(z ? mem : x, z ? Wk : Wq, z ? Kp : Q,
              1024, 1024, blockIdx.y * 128, blockIdx.x * 128,
              z ? 1.f : qscale, As, Bs);
}

// ============================================================================
// In-place bf16 row softmax over 2048 logits; one block per row.
// ============================================================================
__global__ __launch_bounds__(256)
void softmax_rows_2048(bf* __restrict__ X)
{
    const long row = blockIdx.x;
    const int t = threadIdx.x;
    const int wave = t >> 6, lane = t & 63;
    __shared__ float red[8];

    float v[8];
    float m = -1e30f;
#pragma unroll
    for (int i = 0; i < 8; i++) {
        v[i] = __bfloat162float(X[row * 2048 + t + i * 256]);
        m = fmaxf(m, v[i]);
    }
#pragma unroll
    for (int o = 32; o > 0; o >>= 1) m = fmaxf(m, __shfl_xor(m, o, 64));
    if (lane == 0) red[wave] = m;
    __syncthreads();
    m = fmaxf(fmaxf(red[0], red[1]), fmaxf(red[2], red[3]));

    float s = 0.f;
#pragma unroll
    for (int i = 0; i < 8; i++) { v[i] = __expf(v[i] - m); s += v[i]; }
#pragma unroll
    for (int o = 32; o > 0; o >>= 1) s += __shfl_xor(s, o, 64);
    if (lane == 0) red[4 + wave] = s;
    __syncthreads();
    s = red[4] + red[5] + red[6] + red[7];

    const float inv = 1.f / s;
#pragma unroll
    for (int i = 0; i < 8; i++)
        X[row * 2048 + t + i * 256] = __float2bfloat16(v[i] * inv);
}

// ============================================================================
// Pipeline (9 dispatches):
//   1. QK fused proj (z=2, 1024 blk)      x,mem fp32 -> Q,Kp bf16
//   2. Vt proj       (z=4,  512 blk)      Vt[b][e,m] = Wv[e,:].mem[b][m,:]
//   3. per batch-PAIR g in {0,1}:
//        logits z=2 (512 blk) -> Lg bf16 [2][2048][2048]
//        softmax (4096 blk) in-place
//        AO z=2     (256 blk) -> AO bf16 (aliases Q: Q[pair g] dead)
//   4. final proj    (512 blk)            out fp32
// Workspace: Q/AO 16 + Kp 16 + Vt 16 + Lg 16 = 64 MiB (proven safe in R5/R6).
// ============================================================================
extern "C" void kernel_launch(void* const* d_in, const int* in_sizes, int n_in,
                              void* d_out, int out_size, void* d_ws, size_t ws_size,
                              hipStream_t stream)
{
    const float* x   = (const float*)d_in[0];  // [4,2048,1024] fp32
    const float* mem = (const float*)d_in[1];
    const float* Wq  = (const float*)d_in[2];  // [1024,1024] fp32 [out,in]
    const float* Wk  = (const float*)d_in[3];
    const float* Wv  = (const float*)d_in[4];
    const float* Wo  = (const float*)d_in[5];
    float* out = (float*)d_out;                // fp32 reference output

    constexpr int  B = 4, L = 2048, D = 1024;
    constexpr long LD = (long)L * D;
    constexpr long LL = (long)L * L;
    constexpr size_t CH = 1u << 24;

    char* ws = (char*)d_ws;
    bf* Q  = (bf*)(ws + 0 * CH);   // [4][2048][1024]; AO aliases
    bf* Kp = (bf*)(ws + 1 * CH);   // [4][2048][1024]
    bf* Vt = (bf*)(ws + 2 * CH);   // [4][1024][2048]
    bf* Lg = (bf*)(ws + 3 * CH);   // [2][2048][2048] logits -> P in place
    bf* AO = Q;

    dim3 blk(256);
    const float qscale = 0.03125f;  // 1024^-0.5

    // 1. Q = x@Wq^T*s, K = mem@Wk^T
    gemm_qk<<<dim3(D / 128, B * L / 128, 2), blk, 0, stream>>>(
        x, mem, Wq, Wk, Q, Kp, qscale);

    // 2. Vt[b] = Wv (.) mem[b]^T : M=D, N=L, K=D
    gemm_z<float, float, bf><<<dim3(L / 128, D / 128, B), blk, 0, stream>>>(
        Wv, mem, Vt, D, L, 0, LD, (long)D * L, 1.f);

    for (int g = 0; g < 2; g++) {
        bf* Qg  = Q  + (long)g * 2 * LD;
        bf* Kg  = Kp + (long)g * 2 * LD;
        bf* Vg  = Vt + (long)g * 2 * (long)D * L;
        bf* AOg = AO + (long)g * 2 * LD;
        // logits[z][q,m] = Qg[z][q,:].Kg[z][m,:] : M=N=L, K=D
        gemm_z<bf, bf, bf><<<dim3(L / 128, L / 128, 2), blk, 0, stream>>>(
            Qg, Kg, Lg, D, L, LD, LD, LL, 1.f);
        softmax_rows_2048<<<dim3(2 * L), blk, 0, stream>>>(Lg);
        // AO[z][q,e] = P[z][q,:].Vg[z][e,:] : M=L, N=D, K=L
        gemm_z<bf, bf, bf><<<dim3(D / 128, L / 128, 2), blk, 0, stream>>>(
            Lg, Vg, AOg, L, D, LL, (long)D * L, LD, 1.f);
    }

    // 4. out = AO @ Wo^T : M=B*L, N=D, K=D
    gemm_z<bf, float, float><<<dim3(D / 128, B * L / 128, 1), blk, 0, stream>>>(
        AO, Wo, out, D, D, 0, 0, 0, 1.f);
}